// Round 1
// baseline (412.101 us; speedup 1.0000x reference)
//
#include <hip/hip_runtime.h>

#define ADAM_B1 0.9f
#define ADAM_B2 0.999f
#define ADAM_LR 1e-3f
#define ADAM_EPS 1e-8f

// K1: one wave (64 lanes) per occurrence. Lane 0 increments counts[row];
// all lanes zero the row of d_out (used as gsum scratch). Duplicate rows
// race writing zeros -- benign.
__global__ void k_count_zero(const int* __restrict__ idx, float* __restrict__ out,
                             unsigned* __restrict__ counts, int n_idx, int D) {
    int wave = (int)((blockIdx.x * (unsigned)blockDim.x + threadIdx.x) >> 6);
    int lane = threadIdx.x & 63;
    if (wave >= n_idx) return;
    int row = idx[wave];
    if (lane == 0) atomicAdd(&counts[row], 1u);
    float2* o = (float2*)(out + (long long)row * D);
    int nv = D >> 1;
    for (int c = lane; c < nv; c += 64)
        o[c] = make_float2(0.f, 0.f);
}

// K2: one thread per (occurrence, col) element; atomic scatter-add of grads
// into d_out (gsum).
__global__ void k_scatter(const int* __restrict__ idx, const float* __restrict__ grad,
                          float* __restrict__ out, long long total, int D) {
    long long i = (long long)blockIdx.x * blockDim.x + threadIdx.x;
    if (i >= total) return;
    int occ = (int)(i / D);
    int col = (int)(i - (long long)occ * D);
    int row = idx[occ];
    atomicAdd(&out[(long long)row * D + col], grad[i]);
}

// K3: one wave per table row, float2 per lane. Wave-uniform fast path for
// untouched rows (pure copy, skips state reads).
__global__ void k_adam(const float* __restrict__ emb,
                       const float* __restrict__ step_,
                       const float* __restrict__ mem_,
                       const float* __restrict__ pow_,
                       const unsigned* __restrict__ counts,
                       float* __restrict__ out, int n_emb, int D) {
    int wave = (int)((blockIdx.x * (unsigned)blockDim.x + threadIdx.x) >> 6);
    int lane = threadIdx.x & 63;
    if (wave >= n_emb) return;
    long long base = (long long)wave * D;
    unsigned cnt = counts[wave];
    const float2* e2 = (const float2*)(emb + base);
    float2* o2 = (float2*)(out + base);
    int nv = D >> 1;
    if (cnt == 0) {
        for (int c = lane; c < nv; c += 64) o2[c] = e2[c];
        return;
    }
    float inv_cnt = 1.0f / (float)cnt;
    float stepn = step_[wave] + 1.0f;
    float d1 = 1.0f - powf(ADAM_B1, stepn);
    float d2 = 1.0f - powf(ADAM_B2, stepn);
    float inv_d1 = 1.0f / d1;
    float inv_d2 = 1.0f / d2;
    const float2* m2 = (const float2*)(mem_ + base);
    const float2* p2 = (const float2*)(pow_ + base);
    for (int c = lane; c < nv; c += 64) {
        float2 g = o2[c];                  // gsum accumulated by K2
        g.x *= inv_cnt; g.y *= inv_cnt;    // gmean
        float2 m = m2[c];
        float2 p = p2[c];
        float2 e = e2[c];
        float mx = ADAM_B1 * m.x + (1.0f - ADAM_B1) * g.x;
        float my = ADAM_B1 * m.y + (1.0f - ADAM_B1) * g.y;
        float px = ADAM_B2 * p.x + (1.0f - ADAM_B2) * g.x * g.x;
        float py = ADAM_B2 * p.y + (1.0f - ADAM_B2) * g.y * g.y;
        float sx = ADAM_LR * (mx * inv_d1) / (sqrtf(px * inv_d2) + ADAM_EPS);
        float sy = ADAM_LR * (my * inv_d1) / (sqrtf(py * inv_d2) + ADAM_EPS);
        o2[c] = make_float2(e.x - sx, e.y - sy);
    }
}

extern "C" void kernel_launch(void* const* d_in, const int* in_sizes, int n_in,
                              void* d_out, int out_size, void* d_ws, size_t ws_size,
                              hipStream_t stream) {
    const int*   idx   = (const int*)d_in[0];
    const float* grad  = (const float*)d_in[1];
    const float* emb   = (const float*)d_in[2];
    const float* step_ = (const float*)d_in[3];
    const float* mem_  = (const float*)d_in[4];
    const float* pow_  = (const float*)d_in[5];
    float* out = (float*)d_out;

    int n_idx = in_sizes[0];
    int n_emb = in_sizes[3];               // state_step is [N_EMB]
    int D     = in_sizes[1] / n_idx;       // 128

    unsigned* counts = (unsigned*)d_ws;    // n_emb * 4 bytes
    hipMemsetAsync(counts, 0, (size_t)n_emb * sizeof(unsigned), stream);

    const int blk = 256;

    long long t1 = (long long)n_idx * 64;
    k_count_zero<<<(int)((t1 + blk - 1) / blk), blk, 0, stream>>>(idx, out, counts, n_idx, D);

    long long total = (long long)n_idx * D;
    k_scatter<<<(int)((total + blk - 1) / blk), blk, 0, stream>>>(idx, grad, out, total, D);

    long long t3 = (long long)n_emb * 64;
    k_adam<<<(int)((t3 + blk - 1) / blk), blk, 0, stream>>>(emb, step_, mem_, pow_, counts, out, n_emb, D);
}

// Round 2
// 373.069 us; speedup vs baseline: 1.1046x; 1.1046x over previous
//
#include <hip/hip_runtime.h>

#define ADAM_B1 0.9f
#define ADAM_B2 0.999f
#define ADAM_LR 1e-3f
#define ADAM_EPS 1e-8f

// K1: one thread per occurrence. Build per-row linked list of occurrences:
//   next[occ] = atomicExch(&head[row], occ)
// head[] must be -1-initialized (memset 0xFF) before this kernel.
__global__ void k_build_list(const int* __restrict__ idx, int* __restrict__ head,
                             int* __restrict__ next_, int n_idx) {
    int i = blockIdx.x * blockDim.x + threadIdx.x;
    if (i >= n_idx) return;
    int row = idx[i];
    next_[i] = atomicExch(&head[row], i);
}

// K2: fused sparse Adam. One half-wave (32 lanes) per table row, float4/lane.
// Untouched rows (head<0): pure emb->out copy, no state reads.
// Touched rows: walk the occurrence chain (avg ~1.13 hops), accumulate grad
// sum in registers, then Adam update.
__global__ void k_adam_fused(const float* __restrict__ emb,
                             const float* __restrict__ step_,
                             const float* __restrict__ mem_,
                             const float* __restrict__ pow_,
                             const float* __restrict__ grad,
                             const int* __restrict__ head,
                             const int* __restrict__ next_,
                             float* __restrict__ out, int n_emb, int D) {
    int gid = blockIdx.x * blockDim.x + threadIdx.x;
    int row = gid >> 5;                 // one half-wave per row
    int lane = threadIdx.x & 31;
    if (row >= n_emb) return;
    long long base = (long long)row * D;
    const float4* e4 = (const float4*)(emb + base);
    float4* o4 = (float4*)(out + base);
    int nv = D >> 2;                    // float4s per row (32 for D=128)

    int h = head[row];
    if (h < 0) {
        // untouched: straight copy
        for (int c = lane; c < nv; c += 32) o4[c] = e4[c];
        return;
    }

    // walk chain: sum grads + count occurrences (registers only)
    float cnt = 0.0f;
    for (int c = lane; c < nv; c += 32) {
        float4 g = make_float4(0.f, 0.f, 0.f, 0.f);
        int p = h;
        float k = 0.0f;
        while (p >= 0) {
            const float4* g4 = (const float4*)(grad + (long long)p * D);
            float4 gv = g4[c];
            g.x += gv.x; g.y += gv.y; g.z += gv.z; g.w += gv.w;
            k += 1.0f;
            p = next_[p];
        }
        cnt = k;

        float inv_cnt = 1.0f / cnt;
        g.x *= inv_cnt; g.y *= inv_cnt; g.z *= inv_cnt; g.w *= inv_cnt;

        float stepn = step_[row] + 1.0f;
        // pow(b, s) = exp2(s * log2(b)) -- single v_exp_f32 each
        const float L2B1 = -0.15200309344504997f;     // log2(0.9)
        const float L2B2 = -0.0014434592066161948f;   // log2(0.999)
        float d1 = 1.0f - exp2f(stepn * L2B1);
        float d2 = 1.0f - exp2f(stepn * L2B2);
        float inv_d1 = 1.0f / d1;
        float inv_d2 = 1.0f / d2;

        const float4* m4 = (const float4*)(mem_ + base);
        const float4* p4 = (const float4*)(pow_ + base);
        float4 m = m4[c];
        float4 pv = p4[c];
        float4 e = e4[c];

        float4 r;
        {
            float mx = ADAM_B1 * m.x + (1.0f - ADAM_B1) * g.x;
            float px = ADAM_B2 * pv.x + (1.0f - ADAM_B2) * g.x * g.x;
            r.x = e.x - ADAM_LR * (mx * inv_d1) / (sqrtf(px * inv_d2) + ADAM_EPS);
            float my = ADAM_B1 * m.y + (1.0f - ADAM_B1) * g.y;
            float py = ADAM_B2 * pv.y + (1.0f - ADAM_B2) * g.y * g.y;
            r.y = e.y - ADAM_LR * (my * inv_d1) / (sqrtf(py * inv_d2) + ADAM_EPS);
            float mz = ADAM_B1 * m.z + (1.0f - ADAM_B1) * g.z;
            float pz = ADAM_B2 * pv.z + (1.0f - ADAM_B2) * g.z * g.z;
            r.z = e.z - ADAM_LR * (mz * inv_d1) / (sqrtf(pz * inv_d2) + ADAM_EPS);
            float mw = ADAM_B1 * m.w + (1.0f - ADAM_B1) * g.w;
            float pw = ADAM_B2 * pv.w + (1.0f - ADAM_B2) * g.w * g.w;
            r.w = e.w - ADAM_LR * (mw * inv_d1) / (sqrtf(pw * inv_d2) + ADAM_EPS);
        }
        o4[c] = r;
    }
}

extern "C" void kernel_launch(void* const* d_in, const int* in_sizes, int n_in,
                              void* d_out, int out_size, void* d_ws, size_t ws_size,
                              hipStream_t stream) {
    const int*   idx   = (const int*)d_in[0];
    const float* grad  = (const float*)d_in[1];
    const float* emb   = (const float*)d_in[2];
    const float* step_ = (const float*)d_in[3];
    const float* mem_  = (const float*)d_in[4];
    const float* pow_  = (const float*)d_in[5];
    float* out = (float*)d_out;

    int n_idx = in_sizes[0];
    int n_emb = in_sizes[3];               // state_step is [N_EMB]
    int D     = in_sizes[1] / n_idx;       // 128

    int* head  = (int*)d_ws;               // n_emb ints
    int* next_ = head + n_emb;             // n_idx ints

    hipMemsetAsync(head, 0xFF, (size_t)n_emb * sizeof(int), stream);  // all -1

    const int blk = 256;
    k_build_list<<<(n_idx + blk - 1) / blk, blk, 0, stream>>>(idx, head, next_, n_idx);

    long long threads = (long long)n_emb * 32;   // one half-wave per row
    k_adam_fused<<<(int)((threads + blk - 1) / blk), blk, 0, stream>>>(
        emb, step_, mem_, pow_, grad, head, next_, out, n_emb, D);
}